// Round 3
// baseline (1667.962 us; speedup 1.0000x reference)
//
#include <hip/hip_runtime.h>
#include <math.h>

#define NYg 1024
#define NXg 1024
#define NSTEPS 64
#define NSLOT 8            // max-reduction slots per step (one per XCD group)
#define SLOT_STRIDE 32     // dwords between slots (128 B lines)
#define SLOT_GROUP (NSLOT * SLOT_STRIDE)
#define NSLOTGROUPS (NSTEPS + 1)

constexpr float DXf   = 50.0f;
constexpr float DYf   = 50.0f;
constexpr float TTOTf = 32.0f;
constexpr float DTMAXf= 0.5f;
constexpr float EPSf  = 1e-10f;
constexpr float TFREQ = 5.0f;
constexpr float LAPSE = 0.0065f;
constexpr float MELTF = 0.5f;
constexpr double RHOG = 910.0 * 9.81;
constexpr float  CDf  = (float)(1e-17 * RHOG * RHOG * RHOG);

// ---- ws layout (dword offsets) ----
#define WS_SLOTS 0
#define WS_XCTR  (WS_SLOTS + NSLOTGROUPS * SLOT_GROUP)   // 8 counters, stride 32 dwords
#define WS_ROOT  (WS_XCTR + 8 * 32)
#define WS_FLAG  (WS_ROOT + 32)
#define WS_CTRL_END (WS_FLAG + 32)
#define WS_GRIDS 32768     // float offset where the 1M-float grids begin
#define GRID_N   (NYg * NXg)

// ---------------- init: zero control, H buffers; Z buffers = ztopo; smbA ----------------
__global__ __launch_bounds__(256) void k_init(
    const float* __restrict__ precip, const float* __restrict__ tma,
    const float* __restrict__ tmj, const float* __restrict__ ztopo,
    const float* __restrict__ mask,
    float* __restrict__ Ha, float* __restrict__ Hb,
    float* __restrict__ Za, float* __restrict__ Zb,
    float* __restrict__ smbA, unsigned int* __restrict__ ctrl)
{
    int idx = blockIdx.x * blockDim.x + threadIdx.x;
    int stride = gridDim.x * blockDim.x;
    float TMA = tma[0], TMJ = tmj[0];
    for (int i = idx; i < GRID_N; i += stride) {
        float z = ztopo[i];
        Ha[i] = 0.0f;
        Hb[i] = 0.0f;
        Za[i] = z;
        Zb[i] = z;
        float t_ma = TMA - LAPSE * z;
        float t_mj = TMJ - LAPSE * z;
        float acc  = (t_ma < 0.0f) ? precip[i] : 0.0f;
        float abl  = MELTF * fmaxf(t_mj, 0.0f);
        smbA[i] = (acc - abl) * mask[i];
    }
    for (int i = idx; i < WS_CTRL_END; i += stride) ctrl[i] = 0u;
}

// ---------------- grid barrier: two-level (8 groups of 32) + release flag ----------------
__device__ inline void gridbar(unsigned int* xctr, unsigned int* root,
                               unsigned int* flag, int xcd, unsigned int gen)
{
    __syncthreads();
    if (threadIdx.x == 0) {
        unsigned int o = __hip_atomic_fetch_add(&xctr[xcd * 32], 1u,
                             __ATOMIC_ACQ_REL, __HIP_MEMORY_SCOPE_AGENT);
        if (o == 31u) {
            __hip_atomic_store(&xctr[xcd * 32], 0u,
                               __ATOMIC_RELAXED, __HIP_MEMORY_SCOPE_AGENT);
            unsigned int r = __hip_atomic_fetch_add(root, 1u,
                                 __ATOMIC_ACQ_REL, __HIP_MEMORY_SCOPE_AGENT);
            if (r == 7u) {
                __hip_atomic_store(root, 0u,
                                   __ATOMIC_RELAXED, __HIP_MEMORY_SCOPE_AGENT);
                __hip_atomic_store(flag, gen,
                                   __ATOMIC_RELEASE, __HIP_MEMORY_SCOPE_AGENT);
            }
        }
        while (__hip_atomic_load(flag, __ATOMIC_RELAXED,
                                 __HIP_MEMORY_SCOPE_AGENT) < gen)
            __builtin_amdgcn_s_sleep(4);
        __threadfence();   // acquire: stale-line invalidate before reading others' data
    }
    __syncthreads();
}

// ---------------- persistent kernel: all 64 steps ----------------
__global__ __launch_bounds__(256, 1) void k_run(
    float* __restrict__ Ha, float* __restrict__ Hb,
    float* __restrict__ Za, float* __restrict__ Zb,
    float* __restrict__ Da, float* __restrict__ Db,
    float* __restrict__ smbA, float* __restrict__ smbB,
    const float* __restrict__ ztopo, const float* __restrict__ precip,
    const float* __restrict__ mask, const float* __restrict__ tma,
    const float* __restrict__ tmj, unsigned int* __restrict__ ctrl)
{
    __shared__ float sH[5][NXg];
    __shared__ float sZ[5][NXg];
    __shared__ float sbc[8];

    unsigned int* slots = ctrl + WS_SLOTS;
    unsigned int* xctr  = ctrl + WS_XCTR;
    unsigned int* root  = ctrl + WS_ROOT;
    unsigned int* flag  = ctrl + WS_FLAG;

    const int xcd = blockIdx.x & 7;
    const int loc = blockIdx.x >> 3;
    const int r0  = xcd * 128 + loc * 4;    // band of 4 owned rows
    const int lane = threadIdx.x & 63, wid = threadIdx.x >> 6;

    const float TMA = tma[0], TMJ = tmj[0];

    float *Hc = Ha, *Hn = Hb, *Zc = Za, *Zn = Zb, *Dc = Da, *Dn = Db;
    float *smbc = smbA, *smbn = smbB;

    // ---- D-phase lambda: compute D for own staggered rows from LDS state, store, return partial max
    auto dphase = [&](float* Dst) -> float {
        float m = 0.0f;
        for (int rr = 0; rr < 4; ++rr) {
            int i = r0 + rr;
            if (i > NYg - 2) break;
            for (int j = threadIdx.x; j < NXg - 1; j += 256) {
                float h00 = sH[rr][j],     h01 = sH[rr][j + 1];
                float h10 = sH[rr + 1][j], h11 = sH[rr + 1][j + 1];
                float z00 = sZ[rr][j],     z01 = sZ[rr][j + 1];
                float z10 = sZ[rr + 1][j], z11 = sZ[rr + 1][j + 1];
                float havg = 0.25f * (h00 + h11 + h01 + h10);
                float sx = ((z01 - z00) + (z11 - z10)) * (0.5f / DXf);
                float sy = ((z10 - z00) + (z11 - z01)) * (0.5f / DYf);
                float sn = sqrtf(sx * sx + sy * sy + EPSf);
                float h2 = havg * havg;
                float h4 = h2 * h2;
                float d = CDf * (h4 * havg) * (sn * sn) + EPSf;
                Dst[i * NXg + j] = d;
                m = fmaxf(m, d);
            }
        }
        return m;
    };

    auto reduce_slot = [&](float m, int grp) {
        #pragma unroll
        for (int off = 32; off >= 1; off >>= 1)
            m = fmaxf(m, __shfl_xor(m, off, 64));
        if (lane == 0) sbc[4 + wid] = m;
        __syncthreads();
        if (threadIdx.x == 0) {
            m = fmaxf(fmaxf(sbc[4], sbc[5]), fmaxf(sbc[6], sbc[7]));
            atomicMax(&slots[grp * SLOT_GROUP + xcd * SLOT_STRIDE], __float_as_uint(m));
        }
    };

    // ---- pre-loop: load state(0) into LDS, compute D(0) + slot group 0 ----
    for (int rr = 0; rr < 5; ++rr) {
        int r = r0 + rr;
        if (r > NYg - 1) break;
        #pragma unroll
        for (int k = 0; k < 4; ++k) {
            int c = threadIdx.x + k * 256;
            int idx = r * NXg + c;
            sH[rr][c] = Hc[idx];
            sZ[rr][c] = Zc[idx];
        }
    }
    __syncthreads();
    reduce_slot(dphase(Dc), 0);
    gridbar(xctr, root, flag, xcd, 1u);

    float t = 0.0f, tl = 0.0f;

    for (int s = 0; s < NSTEPS; ++s) {
        // ---- broadcast max(D(s)) ----
        if (threadIdx.x == 0) {
            unsigned int mb = slots[s * SLOT_GROUP];
            #pragma unroll
            for (int q = 1; q < NSLOT; ++q)
                mb = max(mb, slots[s * SLOT_GROUP + q * SLOT_STRIDE]);
            sbc[0] = __uint_as_float(mb);
        }
        __syncthreads();
        float mD = sbc[0];
        float dt = fminf(2500.0f / (2.7f * mD), DTMAXf);
        if (!(t < TTOTf)) dt = 0.0f;
        float nt  = t + dt;
        bool  upd = (nt - tl) >= TFREQ;

        // ---- update phase: own 4 rows + 1 halo row below; stash state(s+1) in LDS ----
        for (int rr = 0; rr < 5; ++rr) {
            int r = r0 + rr;
            if (r > NYg - 1) break;
            bool irow = (r >= 1 && r <= NYg - 2);
            #pragma unroll
            for (int k = 0; k < 4; ++k) {
                int c = threadIdx.x + k * 256;
                int idx = r * NXg + c;
                float h, z;
                if (irow && c >= 1 && c <= NXg - 2) {
                    float zc = Zc[idx];
                    float zl = Zc[idx - 1],   zr = Zc[idx + 1];
                    float zt = Zc[idx - NXg], zb = Zc[idx + NXg];
                    float d00 = Dc[idx - NXg - 1], d01 = Dc[idx - NXg];
                    float d10 = Dc[idx - 1],       d11 = Dc[idx];
                    float qxR = -0.5f * (d01 + d11) * (zr - zc) * (1.0f / DXf);
                    float qxL = -0.5f * (d00 + d10) * (zc - zl) * (1.0f / DXf);
                    float qyB = -0.5f * (d10 + d11) * (zb - zc) * (1.0f / DYf);
                    float qyT = -0.5f * (d00 + d01) * (zc - zt) * (1.0f / DYf);
                    float dHdt = -((qxR - qxL) * (1.0f / DXf) + (qyB - qyT) * (1.0f / DYf));
                    h = Hc[idx] + dt * (dHdt + smbc[idx]);
                    h = fmaxf(h, 0.0f);
                    z = ztopo[idx] + h;
                    if (rr < 4) { Hn[idx] = h; Zn[idx] = z; }
                } else {
                    h = 0.0f;        // boundary: H stays 0, Z stays Z_topo (pre-init in both buffers)
                    z = Zc[idx];
                }
                sH[rr][c] = h;
                sZ[rr][c] = z;
                if (rr < 4 && upd) {
                    float t_ma = TMA - LAPSE * z;
                    float t_mj = TMJ - LAPSE * z;
                    float acc  = (t_ma < 0.0f) ? precip[idx] : 0.0f;
                    float abl  = MELTF * fmaxf(t_mj, 0.0f);
                    smbn[idx] = (acc - abl) * mask[idx];
                }
            }
        }
        __syncthreads();

        // ---- D(s+1) from LDS-resident state(s+1); then one grid barrier ----
        if (s < NSTEPS - 1) {
            reduce_slot(dphase(Dn), s + 1);
            gridbar(xctr, root, flag, xcd, (unsigned int)(s + 2));
        }

        // ---- advance ----
        { float* tp;
          tp = Hc; Hc = Hn; Hn = tp;
          tp = Zc; Zc = Zn; Zn = tp;
          tp = Dc; Dc = Dn; Dn = tp;
          if (upd) { tp = smbc; smbc = smbn; smbn = tp; } }
        t = nt;
        if (upd) tl = nt;
    }
}

extern "C" void kernel_launch(void* const* d_in, const int* in_sizes, int n_in,
                              void* d_out, int out_size, void* d_ws, size_t ws_size,
                              hipStream_t stream)
{
    const float* precip = (const float*)d_in[0];
    const float* tma    = (const float*)d_in[1];
    const float* tmj    = (const float*)d_in[2];
    const float* ztopo  = (const float*)d_in[3];
    const float* mask   = (const float*)d_in[4];

    float* Ha = (float*)d_out;                     // H parity-0 buffer; H(64) lands here

    unsigned int* ctrl = (unsigned int*)d_ws;      // slots + barrier state
    float* g = (float*)d_ws + WS_GRIDS;
    float* Hb   = g + 0 * GRID_N;
    float* Za   = g + 1 * GRID_N;
    float* Zb   = g + 2 * GRID_N;
    float* Da   = g + 3 * GRID_N;
    float* Db   = g + 4 * GRID_N;
    float* smbA = g + 5 * GRID_N;
    float* smbB = g + 6 * GRID_N;

    k_init<<<dim3(256), dim3(256), 0, stream>>>(precip, tma, tmj, ztopo, mask,
                                                Ha, Hb, Za, Zb, smbA, ctrl);

    k_run<<<dim3(256), dim3(256), 0, stream>>>(Ha, Hb, Za, Zb, Da, Db, smbA, smbB,
                                               ztopo, precip, mask, tma, tmj, ctrl);
}

// Round 5
// 1114.967 us; speedup vs baseline: 1.4960x; 1.4960x over previous
//
#include <hip/hip_runtime.h>
#include <math.h>

#define NYg 1024
#define NXg 1024
#define W   1024
#define NSTEPS 64
#define GRID_N (NYg * W)

// ---- ctrl (dword offsets in d_ws) ----
#define SLOT_STRIDE 32
#define SLOT_GROUP  256              // 8 slots * 32 dwords
#define NSLOTG      (NSTEPS + 1)
#define WS_XCTR (NSLOTG * SLOT_GROUP)
#define WS_ROOT (WS_XCTR + 8 * 32)
#define WS_FLAG (WS_ROOT + 32)
#define WS_CTRL_END (WS_FLAG + 32)
#define WS_GRIDS 32768               // float offset where exchange arrays begin

constexpr float DXf   = 50.0f;
constexpr float DYf   = 50.0f;
constexpr float TTOTf = 32.0f;
constexpr float DTMAXf= 0.5f;
constexpr float EPSf  = 1e-10f;
constexpr float TFREQ = 5.0f;
constexpr float LAPSE = 0.0065f;
constexpr float MELTF = 0.5f;
constexpr double RHOG = 910.0 * 9.81;
constexpr float  CDf  = (float)(1e-17 * RHOG * RHOG * RHOG);

// memory-side (coherence-point) accessors — bypass non-coherent per-XCD L2s
__device__ __forceinline__ float scloadf(const float* p) {
    return __hip_atomic_load(p, __ATOMIC_RELAXED, __HIP_MEMORY_SCOPE_SYSTEM);
}
__device__ __forceinline__ void scstoref(float* p, float v) {
    __hip_atomic_store(p, v, __ATOMIC_RELAXED, __HIP_MEMORY_SCOPE_SYSTEM);
}
__device__ __forceinline__ unsigned scloadu(const unsigned* p) {
    return __hip_atomic_load(p, __ATOMIC_RELAXED, __HIP_MEMORY_SCOPE_SYSTEM);
}

// diffusivity on one staggered cell — expression verbatim from the bit-exact R2 kernel
__device__ __forceinline__ float dfunc(float h00, float h01, float h10, float h11,
                                       float z00, float z01, float z10, float z11)
{
    float havg = 0.25f * (h00 + h11 + h01 + h10);
    float sx = ((z01 - z00) + (z11 - z10)) * (0.5f / DXf);
    float sy = ((z10 - z00) + (z11 - z01)) * (0.5f / DYf);
    float sn = sqrtf(sx * sx + sy * sy + EPSf);
    float h2 = havg * havg;
    float h4 = h2 * h2;
    return CDf * (h4 * havg) * (sn * sn) + EPSf;
}

// ---------------- init: zero ctrl, seed slot group 0 with EPS (D(0)==EPS exactly) ----
__global__ __launch_bounds__(256) void k_init(unsigned* __restrict__ ctrl)
{
    int idx = blockIdx.x * blockDim.x + threadIdx.x;
    int stride = gridDim.x * blockDim.x;
    for (int i = idx; i < WS_CTRL_END; i += stride) {
        unsigned v = 0u;
        if (i < SLOT_GROUP && (i & (SLOT_STRIDE - 1)) == 0) v = __float_as_uint(EPSf);
        ctrl[i] = v;
    }
}

// ---------------- fence-free grid barrier (monotone counters, no resets) ----------------
__device__ __forceinline__ void gridbar(unsigned* xctr, unsigned* root,
                                        unsigned* flag, int grp, unsigned gen)
{
    asm volatile("s_waitcnt vmcnt(0)" ::: "memory");  // every wave drains its exports
    __syncthreads();
    if (threadIdx.x == 0) {
        unsigned o = __hip_atomic_fetch_add(&xctr[grp * 32], 1u,
                         __ATOMIC_RELAXED, __HIP_MEMORY_SCOPE_AGENT);
        if ((o & 31u) == 31u) {
            unsigned r = __hip_atomic_fetch_add(root, 1u,
                             __ATOMIC_RELAXED, __HIP_MEMORY_SCOPE_AGENT);
            if ((r & 7u) == 7u)
                __hip_atomic_store(flag, gen, __ATOMIC_RELAXED,
                                   __HIP_MEMORY_SCOPE_SYSTEM);
        }
        while (scloadu(flag) < gen) __builtin_amdgcn_s_sleep(1);
        asm volatile("" ::: "memory");
    }
    __syncthreads();
}

// ---------------- persistent kernel: all 64 steps, state in LDS, halos memory-side ----
__global__ __launch_bounds__(256, 1) void k_run(
    float* __restrict__ EZ0, float* __restrict__ EZ1,
    float* __restrict__ EH0, float* __restrict__ EH1,
    const float* __restrict__ ztopo, const float* __restrict__ precip,
    const float* __restrict__ mask, const float* __restrict__ tma,
    const float* __restrict__ tmj, unsigned* __restrict__ ctrl,
    float* __restrict__ Hout)
{
    __shared__ float sZ[7][W];   // rows r0-1 .. r0+5 (slots 0..6)
    __shared__ float sH[7][W];
    __shared__ unsigned su[8];
    __shared__ float smax4[4];

    unsigned* slots = ctrl;
    unsigned* xctr  = ctrl + WS_XCTR;
    unsigned* root  = ctrl + WS_ROOT;
    unsigned* flag  = ctrl + WS_FLAG;

    const int tid = threadIdx.x;
    const int b   = blockIdx.x;      // owns rows 4b..4b+3 (+1 redundant halo row)
    const int r0  = b * 4;
    const int grp = b & 7;
    const int lane = tid & 63, wid = tid >> 6;
    const bool hasAbove = (b > 0), hasBelow = (b < 255);

    const float TMA = tma[0], TMJ = tmj[0];

    float smbr[5][4];                // smb for rows r0..r0+4 at this thread's 4 cols
    float hN[5][4], zN[5][4];        // new state staging (registers across syncs)

    // ---- pre-loop: state(0) into LDS, smb(0) into registers ----
    #pragma unroll
    for (int k = 0; k < 4; ++k) {
        int c = tid + k * 256;
        #pragma unroll
        for (int q = 0; q < 7; ++q) {
            int r = r0 - 1 + q;
            float z = (r >= 0 && r <= NYg - 1) ? ztopo[r * W + c] : 0.0f;
            sZ[q][c] = z;
            sH[q][c] = 0.0f;
        }
        #pragma unroll
        for (int rr = 0; rr < 5; ++rr) {
            int r = r0 + rr;
            if (r <= NYg - 1) {
                float z = ztopo[r * W + c];
                float t_ma = TMA - LAPSE * z;
                float t_mj = TMJ - LAPSE * z;
                float acc  = (t_ma < 0.0f) ? precip[r * W + c] : 0.0f;
                float abl  = MELTF * fmaxf(t_mj, 0.0f);
                smbr[rr][k] = (acc - abl) * mask[r * W + c];
            } else smbr[rr][k] = 0.0f;
        }
    }

    float t = 0.0f, tl = 0.0f;

    for (int s = 0; s < NSTEPS; ++s) {
        const float* EZr = (s & 1) ? EZ0 : EZ1;   // written at iter s-1
        float*       EZw = (s & 1) ? EZ1 : EZ0;   // written this iter (state s+1)
        const float* EHr = (s & 1) ? EH0 : EH1;
        float*       EHw = (s & 1) ? EH1 : EH0;

        // ---- A: stage slots + halo rows (state s) ----
        if (tid < 8) su[tid] = scloadu(&slots[s * SLOT_GROUP + tid * SLOT_STRIDE]);
        if (s > 0) {
            #pragma unroll
            for (int k = 0; k < 4; ++k) {
                int c = tid + k * 256;
                if (hasAbove) { sZ[0][c] = scloadf(EZr + (r0 - 1) * W + c);
                                sH[0][c] = scloadf(EHr + (r0 - 1) * W + c); }
                if (hasBelow) { sZ[6][c] = scloadf(EZr + (r0 + 5) * W + c);
                                sH[6][c] = scloadf(EHr + (r0 + 5) * W + c); }
            }
        }
        __syncthreads();

        unsigned mb = su[0];
        #pragma unroll
        for (int q = 1; q < 8; ++q) mb = max(mb, su[q]);
        float mD = __uint_as_float(mb);
        float dt = fminf(2500.0f / (2.7f * mD), DTMAXf);
        if (!(t < TTOTf)) dt = 0.0f;
        float nt  = t + dt;
        bool  upd = (nt - tl) >= TFREQ;

        // ---- C: compute new state into registers (D(s) recomputed from LDS, bit-identical) ----
        #pragma unroll
        for (int k = 0; k < 4; ++k) {
            int c = tid + k * 256;
            int cm = (c >= 1) ? c - 1 : 0;
            int cp = (c <= W - 2) ? c + 1 : W - 1;
            float zmv[7], z0v[7], zpv[7], hmv[7], h0v[7], hpv[7];
            #pragma unroll
            for (int q = 0; q < 7; ++q) {
                zmv[q] = sZ[q][cm]; z0v[q] = sZ[q][c]; zpv[q] = sZ[q][cp];
                hmv[q] = sH[q][cm]; h0v[q] = sH[q][c]; hpv[q] = sH[q][cp];
            }
            float Dm[6], D0[6];   // staggered rows r0-1+q, cols c-1 / c
            #pragma unroll
            for (int q = 0; q < 6; ++q) {
                Dm[q] = dfunc(hmv[q], h0v[q], hmv[q+1], h0v[q+1],
                              zmv[q], z0v[q], zmv[q+1], z0v[q+1]);
                D0[q] = dfunc(h0v[q], hpv[q], h0v[q+1], hpv[q+1],
                              z0v[q], zpv[q], z0v[q+1], zpv[q+1]);
            }
            #pragma unroll
            for (int rr = 0; rr < 5; ++rr) {
                int r = r0 + rr;
                float h, z;
                if (r <= NYg - 1) {
                    if (r >= 1 && r <= NYg - 2 && c >= 1 && c <= NXg - 2) {
                        float zc = z0v[rr+1], zl = zmv[rr+1], zr = zpv[rr+1];
                        float zt = z0v[rr],   zb = z0v[rr+2];
                        float d00 = Dm[rr],   d01 = D0[rr];
                        float d10 = Dm[rr+1], d11 = D0[rr+1];
                        float qxR = -0.5f * (d01 + d11) * (zr - zc) * (1.0f / DXf);
                        float qxL = -0.5f * (d00 + d10) * (zc - zl) * (1.0f / DXf);
                        float qyB = -0.5f * (d10 + d11) * (zb - zc) * (1.0f / DYf);
                        float qyT = -0.5f * (d00 + d01) * (zc - zt) * (1.0f / DYf);
                        float dHdt = -((qxR - qxL) * (1.0f / DXf) + (qyB - qyT) * (1.0f / DYf));
                        h = h0v[rr+1] + dt * (dHdt + smbr[rr][k]);
                        h = fmaxf(h, 0.0f);
                        z = ztopo[r * W + c] + h;
                    } else { h = 0.0f; z = z0v[rr+1]; }   // boundary: H=0, Z=ztopo
                } else { h = 0.0f; z = 0.0f; }
                hN[rr][k] = h; zN[rr][k] = z;
            }
        }
        __syncthreads();   // all reads of old state complete

        // ---- E: write back LDS, export halo rows, refresh smb on upd ----
        #pragma unroll
        for (int k = 0; k < 4; ++k) {
            int c = tid + k * 256;
            #pragma unroll
            for (int rr = 0; rr < 5; ++rr) {
                int r = r0 + rr;
                if (r > NYg - 1) continue;
                float z = zN[rr][k], h = hN[rr][k];
                sZ[rr + 1][c] = z;
                sH[rr + 1][c] = h;
                if ((rr == 1 && hasAbove) || (rr == 3 && hasBelow)) {
                    scstoref(EZw + r * W + c, z);
                    scstoref(EHw + r * W + c, h);
                }
                if (upd) {
                    float t_ma = TMA - LAPSE * z;
                    float t_mj = TMJ - LAPSE * z;
                    float acc  = (t_ma < 0.0f) ? precip[r * W + c] : 0.0f;
                    float abl  = MELTF * fmaxf(t_mj, 0.0f);
                    smbr[rr][k] = (acc - abl) * mask[r * W + c];
                }
            }
        }
        __syncthreads();

        // ---- G: max over D(s+1) on own staggered rows (no store) + barrier ----
        if (s < NSTEPS - 1) {
            float m = 0.0f;
            #pragma unroll
            for (int k = 0; k < 4; ++k) {
                int j = tid + k * 256;
                if (j <= NXg - 2) {
                    float zj[5], zj1[5], hj[5], hj1[5];
                    #pragma unroll
                    for (int q = 0; q < 5; ++q) {
                        zj[q] = sZ[q+1][j]; zj1[q] = sZ[q+1][j+1];
                        hj[q] = sH[q+1][j]; hj1[q] = sH[q+1][j+1];
                    }
                    #pragma unroll
                    for (int rr = 0; rr < 4; ++rr) {
                        int i = r0 + rr;
                        if (i <= NYg - 2) {
                            float d = dfunc(hj[rr], hj1[rr], hj[rr+1], hj1[rr+1],
                                            zj[rr], zj1[rr], zj[rr+1], zj1[rr+1]);
                            m = fmaxf(m, d);
                        }
                    }
                }
            }
            #pragma unroll
            for (int off = 32; off >= 1; off >>= 1)
                m = fmaxf(m, __shfl_xor(m, off, 64));
            if (lane == 0) smax4[wid] = m;
            __syncthreads();
            if (tid == 0) {
                m = fmaxf(fmaxf(smax4[0], smax4[1]), fmaxf(smax4[2], smax4[3]));
                atomicMax(&slots[(s + 1) * SLOT_GROUP + grp * SLOT_STRIDE],
                          __float_as_uint(m));
            }
            gridbar(xctr, root, flag, grp, (unsigned)(s + 1));
        }

        t = nt;
        if (upd) tl = nt;
    }

    // ---- final: H(64) own rows from registers -> d_out ----
    #pragma unroll
    for (int k = 0; k < 4; ++k) {
        int c = tid + k * 256;
        #pragma unroll
        for (int rr = 0; rr < 4; ++rr)
            Hout[(r0 + rr) * W + c] = hN[rr][k];
    }
}

extern "C" void kernel_launch(void* const* d_in, const int* in_sizes, int n_in,
                              void* d_out, int out_size, void* d_ws, size_t ws_size,
                              hipStream_t stream)
{
    const float* precip = (const float*)d_in[0];
    const float* tma    = (const float*)d_in[1];
    const float* tmj    = (const float*)d_in[2];
    const float* ztopo  = (const float*)d_in[3];
    const float* mask   = (const float*)d_in[4];

    unsigned* ctrl = (unsigned*)d_ws;
    float* g = (float*)d_ws + WS_GRIDS;
    float* EZ0 = g + 0 * GRID_N;
    float* EZ1 = g + 1 * GRID_N;
    float* EH0 = g + 2 * GRID_N;
    float* EH1 = g + 3 * GRID_N;

    k_init<<<dim3(64), dim3(256), 0, stream>>>(ctrl);

    k_run<<<dim3(256), dim3(256), 0, stream>>>(EZ0, EZ1, EH0, EH1,
                                               ztopo, precip, mask, tma, tmj,
                                               ctrl, (float*)d_out);
}

// Round 6
// 552.132 us; speedup vs baseline: 3.0209x; 2.0194x over previous
//
#include <hip/hip_runtime.h>
#include <math.h>

#define NYg 1024
#define NXg 1024
#define W   1024
#define NSTEPS 64
#define GRID_N (NYg * W)

// ---- ctrl (dword offsets in d_ws) ----
#define SLOT_STRIDE 32
#define SLOT_GROUP  256              // 8 slots * 32 dwords
#define NSLOTG      (NSTEPS + 1)
#define WS_XCTR (NSLOTG * SLOT_GROUP)
#define WS_ROOT (WS_XCTR + 8 * 32)
#define WS_FLAG (WS_ROOT + 32)
#define WS_CTRL_END (WS_FLAG + 32)
#define WS_GRIDS 32768               // float offset where exchange arrays begin

constexpr float DXf   = 50.0f;
constexpr float DYf   = 50.0f;
constexpr float TTOTf = 32.0f;
constexpr float DTMAXf= 0.5f;
constexpr float EPSf  = 1e-10f;
constexpr float TFREQ = 5.0f;
constexpr float LAPSE = 0.0065f;
constexpr float MELTF = 0.5f;
constexpr double RHOG = 910.0 * 9.81;
constexpr float  CDf  = (float)(1e-17 * RHOG * RHOG * RHOG);

// memory-side (coherence-point) accessors — bypass non-coherent per-XCD L2s
__device__ __forceinline__ float scloadf(const float* p) {
    return __hip_atomic_load(p, __ATOMIC_RELAXED, __HIP_MEMORY_SCOPE_SYSTEM);
}
__device__ __forceinline__ void scstoref(float* p, float v) {
    __hip_atomic_store(p, v, __ATOMIC_RELAXED, __HIP_MEMORY_SCOPE_SYSTEM);
}
__device__ __forceinline__ unsigned scloadu(const unsigned* p) {
    return __hip_atomic_load(p, __ATOMIC_RELAXED, __HIP_MEMORY_SCOPE_SYSTEM);
}

// diffusivity on one staggered cell — expression verbatim from the bit-exact R2 kernel
__device__ __forceinline__ float dfunc(float h00, float h01, float h10, float h11,
                                       float z00, float z01, float z10, float z11)
{
    float havg = 0.25f * (h00 + h11 + h01 + h10);
    float sx = ((z01 - z00) + (z11 - z10)) * (0.5f / DXf);
    float sy = ((z10 - z00) + (z11 - z01)) * (0.5f / DYf);
    float sn = sqrtf(sx * sx + sy * sy + EPSf);
    float h2 = havg * havg;
    float h4 = h2 * h2;
    return CDf * (h4 * havg) * (sn * sn) + EPSf;
}

// ---------------- init: zero ctrl, seed slot group 0 with EPS (D(0)==EPS exactly) ----
__global__ __launch_bounds__(256) void k_init(unsigned* __restrict__ ctrl)
{
    int idx = blockIdx.x * blockDim.x + threadIdx.x;
    int stride = gridDim.x * blockDim.x;
    for (int i = idx; i < WS_CTRL_END; i += stride) {
        unsigned v = 0u;
        if (i < SLOT_GROUP && (i & (SLOT_STRIDE - 1)) == 0) v = __float_as_uint(EPSf);
        ctrl[i] = v;
    }
}

// ---------------- fence-free grid barrier (monotone counters, no resets) ----------------
__device__ __forceinline__ void gridbar(unsigned* xctr, unsigned* root,
                                        unsigned* flag, int grp, unsigned gen)
{
    asm volatile("s_waitcnt vmcnt(0)" ::: "memory");  // every wave drains its exports
    __syncthreads();
    if (threadIdx.x == 0) {
        unsigned o = __hip_atomic_fetch_add(&xctr[grp * 32], 1u,
                         __ATOMIC_RELAXED, __HIP_MEMORY_SCOPE_AGENT);
        if ((o & 31u) == 31u) {
            unsigned r = __hip_atomic_fetch_add(root, 1u,
                             __ATOMIC_RELAXED, __HIP_MEMORY_SCOPE_AGENT);
            if ((r & 7u) == 7u)
                __hip_atomic_store(flag, gen, __ATOMIC_RELAXED,
                                   __HIP_MEMORY_SCOPE_SYSTEM);
        }
        while (scloadu(flag) < gen) __builtin_amdgcn_s_sleep(1);
        asm volatile("" ::: "memory");
    }
    __syncthreads();
}

// ---------------- persistent kernel: 1024 thr/block, 1 col/thread, 4 rows/block ----
__global__ __launch_bounds__(1024, 4) void k_run(
    float* __restrict__ EZ0, float* __restrict__ EZ1,
    float* __restrict__ EH0, float* __restrict__ EH1,
    const float* __restrict__ ztopo, const float* __restrict__ precip,
    const float* __restrict__ mask, const float* __restrict__ tma,
    const float* __restrict__ tmj, unsigned* __restrict__ ctrl,
    float* __restrict__ Hout)
{
    __shared__ float sZ[7][W];    // rows r0-1 .. r0+5  (slots 0..6)
    __shared__ float sH[7][W];
    __shared__ float sD[6][W];    // staggered rows r0-1 .. r0+4 (slots 0..5)
    __shared__ unsigned su[8];
    __shared__ float smax16[16];

    unsigned* slots = ctrl;
    unsigned* xctr  = ctrl + WS_XCTR;
    unsigned* root  = ctrl + WS_ROOT;
    unsigned* flag  = ctrl + WS_FLAG;

    const int c   = threadIdx.x;         // column, 0..1023
    const int b   = blockIdx.x;          // owns rows 4b..4b+3 (+1 redundant)
    const int r0  = b * 4;
    const int grp = b & 7;
    const int lane = c & 63, wid = c >> 6;
    const bool hasAbove = (b > 0), hasBelow = (b < 255);

    const float TMA = tma[0], TMJ = tmj[0];

    float smbr[5], hN[5], zN[5];

    // ---- pre-loop: state(0) into LDS, D(0)=EPS, smb(0) into registers ----
    #pragma unroll
    for (int q = 0; q < 7; ++q) {
        int r = r0 - 1 + q;
        sZ[q][c] = (r >= 0 && r <= NYg - 1) ? ztopo[r * W + c] : 0.0f;
        sH[q][c] = 0.0f;
    }
    #pragma unroll
    for (int q = 0; q < 6; ++q) sD[q][c] = EPSf;
    #pragma unroll
    for (int rr = 0; rr < 5; ++rr) {
        int r = r0 + rr;
        if (r <= NYg - 1) {
            float z = ztopo[r * W + c];
            float t_ma = TMA - LAPSE * z;
            float t_mj = TMJ - LAPSE * z;
            float acc  = (t_ma < 0.0f) ? precip[r * W + c] : 0.0f;
            float abl  = MELTF * fmaxf(t_mj, 0.0f);
            smbr[rr] = (acc - abl) * mask[r * W + c];
        } else smbr[rr] = 0.0f;
    }

    float t = 0.0f, tl = 0.0f;

    for (int s = 0; s < NSTEPS; ++s) {
        const float* EZr = (s & 1) ? EZ0 : EZ1;
        float*       EZw = (s & 1) ? EZ1 : EZ0;
        const float* EHr = (s & 1) ? EH0 : EH1;
        float*       EHw = (s & 1) ? EH1 : EH0;

        // ---- A: import halo rows (state s) + stage slots ----
        if (s > 0) {
            if (hasAbove) { sZ[0][c] = scloadf(EZr + (r0 - 1) * W + c);
                            sH[0][c] = scloadf(EHr + (r0 - 1) * W + c); }
            if (hasBelow) { sZ[6][c] = scloadf(EZr + (r0 + 5) * W + c);
                            sH[6][c] = scloadf(EHr + (r0 + 5) * W + c); }
        }
        if (c < 8) su[c] = scloadu(&slots[s * SLOT_GROUP + c * SLOT_STRIDE]);
        __syncthreads();

        // ---- A2: band-edge staggered D rows (r0-1 and r0+4) + dt ----
        if (c <= NXg - 2) {
            if (r0 - 1 >= 0)
                sD[0][c] = dfunc(sH[0][c], sH[0][c+1], sH[1][c], sH[1][c+1],
                                 sZ[0][c], sZ[0][c+1], sZ[1][c], sZ[1][c+1]);
            if (r0 + 4 <= NYg - 2)
                sD[5][c] = dfunc(sH[5][c], sH[5][c+1], sH[6][c], sH[6][c+1],
                                 sZ[5][c], sZ[5][c+1], sZ[6][c], sZ[6][c+1]);
        }
        unsigned mb = su[0];
        #pragma unroll
        for (int q = 1; q < 8; ++q) mb = max(mb, su[q]);
        float mD = __uint_as_float(mb);
        float dt = fminf(2500.0f / (2.7f * mD), DTMAXf);
        if (!(t < TTOTf)) dt = 0.0f;
        float nt  = t + dt;
        bool  upd = (nt - tl) >= TFREQ;
        __syncthreads();

        // ---- C: update rows r0..r0+4 into registers (D read from LDS) ----
        #pragma unroll
        for (int rr = 0; rr < 5; ++rr) {
            int r = r0 + rr;
            float h, z;
            if (r <= NYg - 1) {
                if (r >= 1 && r <= NYg - 2 && c >= 1 && c <= NXg - 2) {
                    float zc = sZ[rr+1][c];
                    float zl = sZ[rr+1][c-1], zr = sZ[rr+1][c+1];
                    float zt = sZ[rr][c],     zb = sZ[rr+2][c];
                    float d00 = sD[rr][c-1],   d01 = sD[rr][c];
                    float d10 = sD[rr+1][c-1], d11 = sD[rr+1][c];
                    float qxR = -0.5f * (d01 + d11) * (zr - zc) * (1.0f / DXf);
                    float qxL = -0.5f * (d00 + d10) * (zc - zl) * (1.0f / DXf);
                    float qyB = -0.5f * (d10 + d11) * (zb - zc) * (1.0f / DYf);
                    float qyT = -0.5f * (d00 + d01) * (zc - zt) * (1.0f / DYf);
                    float dHdt = -((qxR - qxL) * (1.0f / DXf) + (qyB - qyT) * (1.0f / DYf));
                    h = sH[rr+1][c] + dt * (dHdt + smbr[rr]);
                    h = fmaxf(h, 0.0f);
                    z = ztopo[r * W + c] + h;
                } else { h = 0.0f; z = sZ[rr+1][c]; }   // boundary: H=0, Z=ztopo
            } else { h = 0.0f; z = 0.0f; }
            hN[rr] = h; zN[rr] = z;
        }
        __syncthreads();   // old-state reads complete

        // ---- E: write back LDS, export halo rows (state s+1), smb refresh ----
        #pragma unroll
        for (int rr = 0; rr < 5; ++rr) {
            int r = r0 + rr;
            if (r > NYg - 1) continue;
            float z = zN[rr], h = hN[rr];
            sZ[rr + 1][c] = z;
            sH[rr + 1][c] = h;
            if (rr == 1 && hasAbove) { scstoref(EZw + r * W + c, z);
                                       scstoref(EHw + r * W + c, h); }
            if (rr == 3 && hasBelow) { scstoref(EZw + r * W + c, z);
                                       scstoref(EHw + r * W + c, h); }
            if (upd) {
                float t_ma = TMA - LAPSE * z;
                float t_mj = TMJ - LAPSE * z;
                float acc  = (t_ma < 0.0f) ? precip[r * W + c] : 0.0f;
                float abl  = MELTF * fmaxf(t_mj, 0.0f);
                smbr[rr] = (acc - abl) * mask[r * W + c];
            }
        }
        __syncthreads();

        // ---- G: D(s+1) own staggered rows -> LDS (reused next step) + max + barrier ----
        if (s < NSTEPS - 1) {
            float m = 0.0f;
            if (c <= NXg - 2) {
                #pragma unroll
                for (int rr = 0; rr < 4; ++rr) {
                    int i = r0 + rr;
                    if (i <= NYg - 2) {
                        float d = dfunc(sH[rr+1][c], sH[rr+1][c+1],
                                        sH[rr+2][c], sH[rr+2][c+1],
                                        sZ[rr+1][c], sZ[rr+1][c+1],
                                        sZ[rr+2][c], sZ[rr+2][c+1]);
                        sD[rr + 1][c] = d;
                        m = fmaxf(m, d);
                    }
                }
            }
            #pragma unroll
            for (int off = 32; off >= 1; off >>= 1)
                m = fmaxf(m, __shfl_xor(m, off, 64));
            if (lane == 0) smax16[wid] = m;
            __syncthreads();
            if (c == 0) {
                #pragma unroll
                for (int q = 1; q < 16; ++q) m = fmaxf(m, smax16[q]);
                atomicMax(&slots[(s + 1) * SLOT_GROUP + grp * SLOT_STRIDE],
                          __float_as_uint(m));
            }
            gridbar(xctr, root, flag, grp, (unsigned)(s + 1));
        }

        t = nt;
        if (upd) tl = nt;
    }

    // ---- final: H(64) own rows -> d_out ----
    #pragma unroll
    for (int rr = 0; rr < 4; ++rr)
        Hout[(r0 + rr) * W + c] = hN[rr];
}

extern "C" void kernel_launch(void* const* d_in, const int* in_sizes, int n_in,
                              void* d_out, int out_size, void* d_ws, size_t ws_size,
                              hipStream_t stream)
{
    const float* precip = (const float*)d_in[0];
    const float* tma    = (const float*)d_in[1];
    const float* tmj    = (const float*)d_in[2];
    const float* ztopo  = (const float*)d_in[3];
    const float* mask   = (const float*)d_in[4];

    unsigned* ctrl = (unsigned*)d_ws;
    float* g = (float*)d_ws + WS_GRIDS;
    float* EZ0 = g + 0 * GRID_N;
    float* EZ1 = g + 1 * GRID_N;
    float* EH0 = g + 2 * GRID_N;
    float* EH1 = g + 3 * GRID_N;

    k_init<<<dim3(64), dim3(256), 0, stream>>>(ctrl);

    k_run<<<dim3(256), dim3(1024), 0, stream>>>(EZ0, EZ1, EH0, EH1,
                                                ztopo, precip, mask, tma, tmj,
                                                ctrl, (float*)d_out);
}

// Round 7
// 461.983 us; speedup vs baseline: 3.6104x; 1.1951x over previous
//
#include <hip/hip_runtime.h>
#include <math.h>

#define NYg 1024
#define NXg 1024
#define W   1024
#define NSTEPS 64
#define GRID_N (NYg * W)

// ---- ctrl (dword offsets in d_ws) ----
#define SLOT_STRIDE 32
#define SLOT_GROUP  256               // 8 slots * 32 dwords
#define NSLOTG      (NSTEPS + 1)
#define WS_CNT  (NSLOTG * SLOT_GROUP) // 8 group counters * 32 dwords
#define WS_NBF  (WS_CNT + 8 * 32)     // 256 neighbor flags * 32 dwords
#define WS_CTRL_END (WS_NBF + 256 * 32)
#define WS_GRIDS 32768                // float offset where exchange arrays begin

constexpr float DXf   = 50.0f;
constexpr float DYf   = 50.0f;
constexpr float TTOTf = 32.0f;
constexpr float DTMAXf= 0.5f;
constexpr float EPSf  = 1e-10f;
constexpr float TFREQ = 5.0f;
constexpr float LAPSE = 0.0065f;
constexpr float MELTF = 0.5f;
constexpr double RHOG = 910.0 * 9.81;
constexpr float  CDf  = (float)(1e-17 * RHOG * RHOG * RHOG);

// memory-side (coherence-point) accessors — bypass non-coherent per-XCD L2s
__device__ __forceinline__ float scloadf(const float* p) {
    return __hip_atomic_load(p, __ATOMIC_RELAXED, __HIP_MEMORY_SCOPE_SYSTEM);
}
__device__ __forceinline__ void scstoref(float* p, float v) {
    __hip_atomic_store(p, v, __ATOMIC_RELAXED, __HIP_MEMORY_SCOPE_SYSTEM);
}
__device__ __forceinline__ unsigned scloadu(const unsigned* p) {
    return __hip_atomic_load(p, __ATOMIC_RELAXED, __HIP_MEMORY_SCOPE_SYSTEM);
}

// diffusivity on one staggered cell — expression verbatim from the bit-exact R2 kernel
__device__ __forceinline__ float dfunc(float h00, float h01, float h10, float h11,
                                       float z00, float z01, float z10, float z11)
{
    float havg = 0.25f * (h00 + h11 + h01 + h10);
    float sx = ((z01 - z00) + (z11 - z10)) * (0.5f / DXf);
    float sy = ((z10 - z00) + (z11 - z01)) * (0.5f / DYf);
    float sn = sqrtf(sx * sx + sy * sy + EPSf);
    float h2 = havg * havg;
    float h4 = h2 * h2;
    return CDf * (h4 * havg) * (sn * sn) + EPSf;
}

// ---------------- init: zero ctrl, seed slot group 0 with EPS (D(0)==EPS exactly) ----
__global__ __launch_bounds__(256) void k_init(unsigned* __restrict__ ctrl)
{
    int idx = blockIdx.x * blockDim.x + threadIdx.x;
    int stride = gridDim.x * blockDim.x;
    for (int i = idx; i < WS_CTRL_END; i += stride) {
        unsigned v = 0u;
        if (i < SLOT_GROUP && (i & (SLOT_STRIDE - 1)) == 0) v = __float_as_uint(EPSf);
        ctrl[i] = v;
    }
}

// ---------------- persistent kernel: neighbor-flag pipeline, deferred global max wait ----
__global__ __launch_bounds__(1024, 1) void k_run(
    float* __restrict__ EZ0, float* __restrict__ EZ1,
    float* __restrict__ ED0, float* __restrict__ ED1,
    const float* __restrict__ ztopo, const float* __restrict__ precip,
    const float* __restrict__ mask, const float* __restrict__ tma,
    const float* __restrict__ tmj, unsigned* __restrict__ ctrl,
    float* __restrict__ Hout)
{
    __shared__ float sZ[7][W];    // state rows r0-1 .. r0+5
    __shared__ float sHm[5][W];   // state rows r0 .. r0+4 (halo H rows not needed)
    __shared__ float sD[6][W];    // staggered rows r0-1 .. r0+4
    __shared__ unsigned su[8];
    __shared__ float smax16[16];

    unsigned* slots = ctrl;
    unsigned* cnt   = ctrl + WS_CNT;
    unsigned* nbf   = ctrl + WS_NBF;

    const int c   = threadIdx.x;          // column 0..1023
    const int b   = blockIdx.x;           // owns rows 4b..4b+3 (+1 redundant)
    const int r0  = b * 4;
    const int grp = b & 7;
    const int lane = c & 63, wid = c >> 6;
    const bool hasA = (b > 0), hasB = (b < 255);

    const float TMA = tma[0], TMJ = tmj[0];

    float smbr[5], ztr[5], hN[5];

    // ---- pre-loop: state(0) into LDS; D(0)=EPS; smb(0), ztopo into registers ----
    #pragma unroll
    for (int q = 0; q < 7; ++q) {
        int r = r0 - 1 + q;
        sZ[q][c] = (r >= 0 && r < NYg) ? ztopo[r * W + c] : 0.0f;
    }
    #pragma unroll
    for (int q = 0; q < 5; ++q) sHm[q][c] = 0.0f;
    #pragma unroll
    for (int q = 0; q < 6; ++q) sD[q][c] = EPSf;
    #pragma unroll
    for (int rr = 0; rr < 5; ++rr) {
        int r = r0 + rr;
        if (r < NYg) {
            float z = ztopo[r * W + c];
            ztr[rr] = z;
            float t_ma = TMA - LAPSE * z;
            float t_mj = TMJ - LAPSE * z;
            float acc  = (t_ma < 0.0f) ? precip[r * W + c] : 0.0f;
            float abl  = MELTF * fmaxf(t_mj, 0.0f);
            smbr[rr] = (acc - abl) * mask[r * W + c];
        } else { ztr[rr] = 0.0f; smbr[rr] = 0.0f; }
    }
    __syncthreads();

    float t = 0.0f, tl = 0.0f;

    for (int s = 0; s < NSTEPS; ++s) {
        const float* EZr = (s & 1) ? EZ1 : EZ0;   // state s halos
        float*       EZw = (s & 1) ? EZ0 : EZ1;   // state s+1 halos
        const float* EDr = (s & 1) ? ED1 : ED0;   // D(s) edge rows
        float*       EDw = (s & 1) ? ED0 : ED1;   // D(s+1) edge rows

        // ---- A: neighbor-flag wait + halo import (state s z-rows, D(s) edge rows) ----
        if (s > 0) {
            if (c == 0 && hasA)
                while (scloadu(&nbf[(b - 1) * 32]) < (unsigned)s) __builtin_amdgcn_s_sleep(1);
            if (c == 64 && hasB)
                while (scloadu(&nbf[(b + 1) * 32]) < (unsigned)s) __builtin_amdgcn_s_sleep(1);
            __syncthreads();
            if (hasA) { sZ[0][c] = scloadf(EZr + (r0 - 1) * W + c);
                        if (c <= NXg - 2) sD[0][c] = scloadf(EDr + (r0 - 1) * W + c); }
            if (hasB) { sZ[6][c] = scloadf(EZr + (r0 + 5) * W + c);
                        if (c <= NXg - 2) sD[5][c] = scloadf(EDr + (r0 + 4) * W + c); }
            __syncthreads();
        }

        // ---- C1: dHdt (dt-independent) into registers ----
        float dh[5], hOld[5], zOld[5];
        bool inter[5];
        #pragma unroll
        for (int rr = 0; rr < 5; ++rr) {
            int r = r0 + rr;
            float zc = 0.0f, hc = 0.0f, d = 0.0f;
            bool iv = false;
            if (r < NYg) {
                zc = sZ[rr + 1][c];
                hc = sHm[rr][c];
                iv = (r >= 1 && r <= NYg - 2 && c >= 1 && c <= NXg - 2);
                if (iv) {
                    float zl = sZ[rr + 1][c - 1], zr = sZ[rr + 1][c + 1];
                    float zt = sZ[rr][c],         zb = sZ[rr + 2][c];
                    float d00 = sD[rr][c - 1],     d01 = sD[rr][c];
                    float d10 = sD[rr + 1][c - 1], d11 = sD[rr + 1][c];
                    float qxR = -0.5f * (d01 + d11) * (zr - zc) * (1.0f / DXf);
                    float qxL = -0.5f * (d00 + d10) * (zc - zl) * (1.0f / DXf);
                    float qyB = -0.5f * (d10 + d11) * (zb - zc) * (1.0f / DYf);
                    float qyT = -0.5f * (d00 + d01) * (zc - zt) * (1.0f / DYf);
                    d = -((qxR - qxL) * (1.0f / DXf) + (qyB - qyT) * (1.0f / DYf));
                }
            }
            dh[rr] = d; hOld[rr] = hc; zOld[rr] = zc; inter[rr] = iv;
        }

        // ---- W: deferred global-max wait (counters monotone; target 32*s) ----
        if (c < 8) {
            unsigned tgt = 32u * (unsigned)s;
            while (scloadu(&cnt[c * 32]) < tgt) __builtin_amdgcn_s_sleep(1);
            su[c] = scloadu(&slots[s * SLOT_GROUP + c * SLOT_STRIDE]);
        }
        __syncthreads();   // doubles as: all C1 LDS reads complete before E writes

        unsigned mb = su[0];
        #pragma unroll
        for (int q = 1; q < 8; ++q) mb = max(mb, su[q]);
        float mD = __uint_as_float(mb);
        float dt = fminf(2500.0f / (2.7f * mD), DTMAXf);
        if (!(t < TTOTf)) dt = 0.0f;
        float nt  = t + dt;
        bool  upd = (nt - tl) >= TFREQ;

        // ---- C2+E: finalize h/z, write back LDS, export z halo rows, smb refresh ----
        #pragma unroll
        for (int rr = 0; rr < 5; ++rr) {
            int r = r0 + rr;
            float h, z;
            if (r >= NYg)        { h = 0.0f; z = 0.0f; }
            else if (inter[rr])  { h = fmaxf(hOld[rr] + dt * (dh[rr] + smbr[rr]), 0.0f);
                                   z = ztr[rr] + h; }
            else                 { h = 0.0f; z = zOld[rr]; }
            hN[rr] = h;
            if (r < NYg) {
                sZ[rr + 1][c] = z;
                sHm[rr][c]    = h;
                if (rr == 1 && hasA) scstoref(EZw + r * W + c, z);
                if (rr == 3 && hasB) scstoref(EZw + r * W + c, z);
                if (upd) {
                    float t_ma = TMA - LAPSE * z;
                    float t_mj = TMJ - LAPSE * z;
                    float acc  = (t_ma < 0.0f) ? precip[r * W + c] : 0.0f;
                    float abl  = MELTF * fmaxf(t_mj, 0.0f);
                    smbr[rr] = (acc - abl) * mask[r * W + c];
                }
            }
        }
        __syncthreads();   // LDS writeback visible for G

        // ---- G: D(s+1) own staggered rows -> LDS + edge export + max + publish ----
        if (s < NSTEPS - 1) {
            float m = 0.0f;
            #pragma unroll
            for (int rr = 0; rr < 4; ++rr) {
                int i = r0 + rr;
                if (i <= NYg - 2 && c <= NXg - 2) {
                    float d = dfunc(sHm[rr][c], sHm[rr][c + 1],
                                    sHm[rr + 1][c], sHm[rr + 1][c + 1],
                                    sZ[rr + 1][c], sZ[rr + 1][c + 1],
                                    sZ[rr + 2][c], sZ[rr + 2][c + 1]);
                    sD[rr + 1][c] = d;
                    m = fmaxf(m, d);
                    if (rr == 0 && hasA) scstoref(EDw + i * W + c, d);
                    if (rr == 3 && hasB) scstoref(EDw + i * W + c, d);
                }
            }
            asm volatile("s_waitcnt vmcnt(0)" ::: "memory");  // all exports drained
            #pragma unroll
            for (int off = 32; off >= 1; off >>= 1)
                m = fmaxf(m, __shfl_xor(m, off, 64));
            if (lane == 0) smax16[wid] = m;
            __syncthreads();
            if (c == 0) {
                #pragma unroll
                for (int q = 1; q < 16; ++q) m = fmaxf(m, smax16[q]);
                __hip_atomic_fetch_max(&slots[(s + 1) * SLOT_GROUP + grp * SLOT_STRIDE],
                                       __float_as_uint(m),
                                       __ATOMIC_RELAXED, __HIP_MEMORY_SCOPE_SYSTEM);
                asm volatile("s_waitcnt vmcnt(0)" ::: "memory");  // max visible first
                __hip_atomic_fetch_add(&cnt[grp * 32], 1u,
                                       __ATOMIC_RELAXED, __HIP_MEMORY_SCOPE_SYSTEM);
                __hip_atomic_store(&nbf[b * 32], (unsigned)(s + 1),
                                   __ATOMIC_RELAXED, __HIP_MEMORY_SCOPE_SYSTEM);
            }
        }

        t = nt;
        if (upd) tl = nt;
    }

    // ---- final: H(64) own rows -> d_out ----
    #pragma unroll
    for (int rr = 0; rr < 4; ++rr)
        Hout[(r0 + rr) * W + c] = hN[rr];
}

extern "C" void kernel_launch(void* const* d_in, const int* in_sizes, int n_in,
                              void* d_out, int out_size, void* d_ws, size_t ws_size,
                              hipStream_t stream)
{
    const float* precip = (const float*)d_in[0];
    const float* tma    = (const float*)d_in[1];
    const float* tmj    = (const float*)d_in[2];
    const float* ztopo  = (const float*)d_in[3];
    const float* mask   = (const float*)d_in[4];

    unsigned* ctrl = (unsigned*)d_ws;
    float* g = (float*)d_ws + WS_GRIDS;
    float* EZ0 = g + 0 * GRID_N;
    float* EZ1 = g + 1 * GRID_N;
    float* ED0 = g + 2 * GRID_N;
    float* ED1 = g + 3 * GRID_N;

    k_init<<<dim3(64), dim3(256), 0, stream>>>(ctrl);

    k_run<<<dim3(256), dim3(1024), 0, stream>>>(EZ0, EZ1, ED0, ED1,
                                                ztopo, precip, mask, tma, tmj,
                                                ctrl, (float*)d_out);
}